// Round 4
// baseline (482.505 us; speedup 1.0000x reference)
//
#include <hip/hip_runtime.h>
#include <hip/hip_bf16.h>
#include <math.h>

#define NH 16
#define DH 128
#define DM 2048
#define BB 2
#define TT 2048

typedef unsigned short u16;
typedef __attribute__((ext_vector_type(8))) __bf16 bf16x8;
typedef __attribute__((ext_vector_type(8))) u16 u16x8;
typedef __attribute__((ext_vector_type(4))) u16 u16x4;
typedef __attribute__((ext_vector_type(4))) float f32x4;

__device__ __forceinline__ float bf2f(u16 a){
  union { unsigned u; float f; } v; v.u = ((unsigned)a) << 16; return v.f;
}
__device__ __forceinline__ u16 f2bf(float f){
  union { float f; unsigned u; } v; v.f = f;
  unsigned r = v.u + 0x7fffu + ((v.u >> 16) & 1u);  // RNE
  return (u16)(r >> 16);
}

// async global->LDS, 16B per lane. LDS dest = wave-uniform base + lane*16.
typedef const __attribute__((address_space(1))) unsigned int* gas_p;
typedef __attribute__((address_space(3))) unsigned int* las_p;
__device__ __forceinline__ void gl_lds16(const u16* g, u16* lds_uniform_base){
  __builtin_amdgcn_global_load_lds((gas_p)(const void*)g,
                                   (las_p)(void*)lds_uniform_base, 16, 0, 0);
}

#define SB() do{ asm volatile("" ::: "memory"); \
                 __builtin_amdgcn_s_barrier();  \
                 asm volatile("" ::: "memory"); }while(0)
#define WAITV4 asm volatile("s_waitcnt vmcnt(4)" ::: "memory")
#define WAITV0 asm volatile("s_waitcnt vmcnt(0)" ::: "memory")

// ---------------- fp32 -> bf16 elementwise, 4/thread ----------------
__global__ __launch_bounds__(256)
void cvt_f32_bf16(const float* __restrict__ src, u16* __restrict__ dst, int n4){
  const int i = blockIdx.x * 256 + threadIdx.x;
  if (i >= n4) return;
  const f32x4 v = *(const f32x4*)(src + (size_t)i * 4);
  u16x4 o;
  #pragma unroll
  for (int j = 0; j < 4; j++) o[j] = f2bf(v[j]);
  *(u16x4*)(dst + (size_t)i * 4) = o;
}

// ---------------- W fp32 [K,N] -> Wt bf16 [N,K] (single) ----------------
__global__ __launch_bounds__(256)
void transpose2048(const float* __restrict__ W, u16* __restrict__ Wt){
  __shared__ u16 tile[32][33];
  const int tx = threadIdx.x, ty = threadIdx.y;
  const int bx = blockIdx.x * 32, by = blockIdx.y * 32;
  #pragma unroll
  for (int i = 0; i < 32; i += 8)
    tile[ty + i][tx] = f2bf(W[(size_t)(by + ty + i) * DM + bx + tx]);
  __syncthreads();
  #pragma unroll
  for (int i = 0; i < 32; i += 8)
    Wt[(size_t)(bx + ty + i) * DM + by + tx] = tile[tx][ty + i];
}

// ---------------- 3 weights fused via z ----------------
__global__ __launch_bounds__(256)
void transpose3(const float* __restrict__ w0, const float* __restrict__ w1,
                const float* __restrict__ w2, u16* __restrict__ dst){
  __shared__ u16 tile[32][33];
  const int z = blockIdx.z;
  const float* W = (z == 0) ? w0 : (z == 1) ? w1 : w2;
  u16* Wt = dst + (size_t)z * DM * DM;
  const int tx = threadIdx.x, ty = threadIdx.y;
  const int bx = blockIdx.x * 32, by = blockIdx.y * 32;
  #pragma unroll
  for (int i = 0; i < 32; i += 8)
    tile[ty + i][tx] = f2bf(W[(size_t)(by + ty + i) * DM + bx + tx]);
  __syncthreads();
  #pragma unroll
  for (int i = 0; i < 32; i += 8)
    Wt[(size_t)(bx + ty + i) * DM + by + tx] = tile[tx][ty + i];
}

// ---------------- 128x128 GEMM v3: 3-buffer counted-vmcnt pipeline ---------
// vs gemm_bt (m97 structure, 711 TF here): SAME occupancy (48KB LDS -> 3
// blocks/CU), SAME barrier count (64/GEMM), SAME MFMA-per-phase-per-barrier
// density, but loads get ~2 phases of cover instead of zero:
//   body(t): vmcnt(4); s_barrier; stage(t+2 -> buf[(t+2)%3]);
//            frag-reads(buf[t%3]); setprio(1); 16 MFMA; setprio(0)
// Race-freedom: buf[(t+2)%3] last read in body(t-1); all waves' reads
// complete before they cross SB(t), which precedes any stage in body(t).
// Staging-completeness: tile t's 4 loads retire at vmcnt(4) before SB(t).
// vmcnt never drains to 0 until the 2 peeled tail tiles (R2-lesson: keep
// barrier density; R1-lesson: keep occupancy).
// Bank swizzle (R2-proven, conflicts 1.26e7 -> 0): store chunk c of row r at
// c ^ ((r>>1)&3) via pre-swizzled GLOBAL source (LDS dest linear); reads XOR
// the same term.
__global__ __launch_bounds__(256)
void gemm_bt3(const u16* __restrict__ A, const u16* __restrict__ Bt_base,
              void* __restrict__ C0, u16* __restrict__ Ck, u16* __restrict__ Cv,
              int mode0){
  __shared__ u16 As[3][128][32];   // 3 x 8KB
  __shared__ u16 Bs[3][128][32];   // 3 x 8KB
  const int z = blockIdx.z;
  const u16* Bt = Bt_base + (size_t)z * DM * DM;
  void* C = (z == 0) ? C0 : (z == 1) ? (void*)Ck : (void*)Cv;
  const int mode = (z == 0) ? mode0 : (z == 1) ? 3 : 2;

  const int tid = threadIdx.x;
  const int wave = tid >> 6, lane = tid & 63;
  const int wm = wave & 1, wn = wave >> 1;
  const int row16 = lane & 15, quad = lane >> 4;
  const int m0 = blockIdx.x * 128, n0 = blockIdx.y * 128;

  const f32x4 zero = {0.f, 0.f, 0.f, 0.f};
  f32x4 acc[4][4];
  #pragma unroll
  for (int i = 0; i < 4; i++)
    #pragma unroll
    for (int j = 0; j < 4; j++) acc[i][j] = zero;

  // staging lane map: unit = 16 rows x 64B; source chunk pre-swizzled.
  const int srow = lane >> 2;                                   // 0..15
  const int scol = ((lane & 3) ^ ((lane >> 3) & 3)) * 8;        // u16 units
  const u16* aBase = A  + (size_t)(m0 + wave * 32 + srow) * DM + scol;
  const u16* bBase = Bt + (size_t)(n0 + wave * 32 + srow) * DM + scol;

  // fragment-read column (undoes the swizzle)
  const int fcol = (quad ^ ((row16 >> 1) & 3)) * 8;

  #define STG3(bs, ko) do{ \
    gl_lds16(aBase + (ko),                   &As[bs][wave * 32][0]); \
    gl_lds16(aBase + (ko) + 16 * DM,         &As[bs][wave * 32 + 16][0]); \
    gl_lds16(bBase + (ko),                   &Bs[bs][wave * 32][0]); \
    gl_lds16(bBase + (ko) + 16 * DM,         &Bs[bs][wave * 32 + 16][0]); \
  }while(0)

  #define CMP3(bc) do{ \
    bf16x8 af[4], bk[4]; \
    _Pragma("unroll") \
    for (int mt = 0; mt < 4; mt++) \
      af[mt] = *(const bf16x8*)&As[bc][wm * 64 + mt * 16 + row16][fcol]; \
    _Pragma("unroll") \
    for (int nt = 0; nt < 4; nt++) \
      bk[nt] = *(const bf16x8*)&Bs[bc][wn * 64 + nt * 16 + row16][fcol]; \
    __builtin_amdgcn_s_setprio(1); \
    _Pragma("unroll") \
    for (int mt = 0; mt < 4; mt++) \
      _Pragma("unroll") \
      for (int nt = 0; nt < 4; nt++) \
        acc[mt][nt] = __builtin_amdgcn_mfma_f32_16x16x32_bf16(af[mt], bk[nt], acc[mt][nt], 0, 0, 0); \
    __builtin_amdgcn_s_setprio(0); \
  }while(0)

  #define PH3S(bc, bs, ko) do{ WAITV4; SB(); STG3(bs, ko); CMP3(bc); }while(0)
  #define PH3N(bc, WAIT)   do{ WAIT;   SB();               CMP3(bc); }while(0)

  // prologue: tiles 0,1 in flight (8 loads/wave)
  STG3(0, 0);
  STG3(1, 32);

  // steady: t = 0..61 compute tile t, stage tile t+2. 62 = 3*20 + 2.
  int ko = 64;                       // tile(t+2) k-offset in u16 elements
  for (int i = 0; i < 20; ++i){
    PH3S(0, 2, ko); ko += 32;
    PH3S(1, 0, ko); ko += 32;
    PH3S(2, 1, ko); ko += 32;
  }
  PH3S(0, 2, ko); ko += 32;          // t=60, stage tile62 -> buf2
  PH3S(1, 0, ko);                    // t=61, stage tile63 -> buf0
  // tails: t=62 (out = tiles 62,63 -> vmcnt(4) retires 62)
  PH3N(2, WAITV4);
  // t=63 (out = tile 63 only -> must drain to 0)
  PH3N(0, WAITV0);

  #undef PH3S
  #undef PH3N
  #undef STG3
  #undef CMP3

  // epilogue: C/D layout row = quad*4+reg, col = lane&15
  #pragma unroll
  for (int mt = 0; mt < 4; mt++){
    #pragma unroll
    for (int nt = 0; nt < 4; nt++){
      #pragma unroll
      for (int r = 0; r < 4; r++){
        const int m = m0 + wm * 64 + mt * 16 + quad * 4 + r;
        const int n = n0 + wn * 64 + nt * 16 + row16;
        const int b = m >> 11, t = m & (TT - 1);
        const int hh = n >> 7, dh = n & (DH - 1);
        if (mode == 1){
          ((u16*)C)[(((size_t)(b * NH + hh) * TT + t) * DH) + dh] = f2bf(acc[mt][nt][r]);
        } else if (mode == 3){
          const int dhs = dh ^ ((t & 7) << 3);
          ((u16*)C)[(((size_t)(b * NH + hh) * TT + t) * DH) + dhs] = f2bf(acc[mt][nt][r]);
        } else if (mode == 2){
          const int ts = (t & 63) ^ ((dh & 7) << 3);
          ((u16*)C)[(((size_t)(b * NH + hh) * 32 + (t >> 6)) * 8192) + dh * 64 + ts] = f2bf(acc[mt][nt][r]);
        } else {
          ((float*)C)[(size_t)m * DM + n] = acc[mt][nt][r];
        }
      }
    }
  }
}

// ---------------- fused RoPE on q (normal) AND k (swizzled storage) --------
__global__ __launch_bounds__(256)
void rope2(u16* __restrict__ qb, u16* __restrict__ kb, const int* __restrict__ posp){
  const int idx = blockIdx.x * 256 + threadIdx.x;   // one per (row, pair-slot)
  const int pair = idx & 63;
  const int row = idx >> 6;                          // b*H*T + h*T + t
  const int t = row & (TT - 1);
  int p0 = *posp; if (p0 < 0) p0 = 0;
  const float tf = (float)(p0 + t);
  const size_t base = (size_t)row * DH;
  // q: storage pair == logical pair
  {
    const float inv = expf(-(float)pair * (9.2103403719761836f / 64.f));
    float sn, cs; sincosf(tf * inv, &sn, &cs);
    const float q1 = bf2f(qb[base + pair]);
    const float q2 = bf2f(qb[base + 64 + pair]);
    qb[base + pair]      = f2bf(q1 * cs - q2 * sn);
    qb[base + 64 + pair] = f2bf(q1 * sn + q2 * cs);
  }
  // k: storage slot `pair` holds logical dh = pair ^ ((t&7)<<3)
  {
    const int pl = pair ^ ((t & 7) << 3);
    const float inv = expf(-(float)pl * (9.2103403719761836f / 64.f));
    float sn, cs; sincosf(tf * inv, &sn, &cs);
    const float k1 = bf2f(kb[base + pair]);
    const float k2 = bf2f(kb[base + 64 + pair]);
    kb[base + pair]      = f2bf(k1 * cs - k2 * sn);
    kb[base + 64 + pair] = f2bf(k1 * sn + k2 * cs);
  }
}

// ---------------- causal flash attention v6 + T5 setprio -------------------
template<bool MASK>
__device__ __forceinline__ void attn_tile(
    int kt0, int qbase, int wave, int row16, int quad,
    const bf16x8 (&qf)[4],
    u16 (&k_s)[64][128], u16 (&vt_s)[128][64], u16 (&p_s)[4][16][72],
    f32x4 (&o_acc)[8], float (&l_acc)[4])
{
  const float scale = 0.08838834764831845f;  // 1/sqrt(128)
  const f32x4 zero = {0.f, 0.f, 0.f, 0.f};
  const int fx = (row16 & 7) << 3;           // XOR de-swizzle
  f32x4 s_acc[4];
  #pragma unroll
  for (int nt = 0; nt < 4; nt++) s_acc[nt] = zero;
  __builtin_amdgcn_s_setprio(1);
  #pragma unroll
  for (int st = 0; st < 4; st++)
    #pragma unroll
    for (int nt = 0; nt < 4; nt++){
      const bf16x8 kf = *(const bf16x8*)&k_s[nt * 16 + row16][(st * 32 + quad * 8) ^ fx];
      s_acc[nt] = __builtin_amdgcn_mfma_f32_16x16x32_bf16(qf[st], kf, s_acc[nt], 0, 0, 0);
    }
  __builtin_amdgcn_s_setprio(0);
  #pragma unroll
  for (int r = 0; r < 4; r++){
    float ps = 0.f;
    #pragma unroll
    for (int nt = 0; nt < 4; nt++){
      float p = __expf(s_acc[nt][r] * scale);
      if (MASK){
        const int qr = qbase + quad * 4 + r;
        if (kt0 + nt * 16 + row16 > qr) p = 0.f;
      }
      ps += p;
      p_s[wave][quad * 4 + r][nt * 16 + row16] = f2bf(p);
    }
    l_acc[r] += ps;
  }
  asm volatile("" ::: "memory");  // p_s wave-private; DS in-order per wave

  __builtin_amdgcn_s_setprio(1);
  #pragma unroll
  for (int kk = 0; kk < 2; kk++){
    const bf16x8 pf = *(const bf16x8*)&p_s[wave][row16][kk * 32 + quad * 8];
    #pragma unroll
    for (int nd = 0; nd < 8; nd++){
      const bf16x8 vb = *(const bf16x8*)&vt_s[nd * 16 + row16][(kk * 32 + quad * 8) ^ fx];
      o_acc[nd] = __builtin_amdgcn_mfma_f32_16x16x32_bf16(pf, vb, o_acc[nd], 0, 0, 0);
    }
  }
  __builtin_amdgcn_s_setprio(0);
}

__global__ __launch_bounds__(256)
void attn_fwd(const u16* __restrict__ q, const u16* __restrict__ k,
              const u16* __restrict__ vtg, u16* __restrict__ ctx){
  __shared__ u16 k_s[64][128];     // dense [key][dh'], DMA-staged
  __shared__ u16 vt_s[128][64];    // dense [dh][t'], DMA-staged
  __shared__ u16 p_s[4][16][72];   // per-wave P [q][key]
  const int tid = threadIdx.x;
  const int wave = tid >> 6, lane = tid & 63;
  const int row16 = lane & 15, quad = lane >> 4;
  const int bh = blockIdx.y;
  const int q0 = (31 - blockIdx.x) * 64;   // heavy blocks dispatch first
  const int qbase = q0 + wave * 16;
  const size_t bho = (size_t)bh * TT * DH;

  bf16x8 qf[4];
  {
    const u16* qp = q + bho + (size_t)(qbase + row16) * DH + quad * 8;
    #pragma unroll
    for (int st = 0; st < 4; st++) qf[st] = *(const bf16x8*)(qp + st * 32);
  }

  float l_acc[4] = {0.f, 0.f, 0.f, 0.f};
  const f32x4 zero = {0.f, 0.f, 0.f, 0.f};
  f32x4 o_acc[8];
  #pragma unroll
  for (int i = 0; i < 8; i++) o_acc[i] = zero;

  // DMA lane maps: K 1KB = 4 rows x 256B; V 1KB = 8 rows x 128B
  const int kl_r = lane >> 4, kl_c = (lane & 15) * 8;
  const int vl_r = lane >> 3, vl_c = (lane & 7) * 8;

  for (int kt0 = 0; kt0 < q0 + 64; kt0 += 64){
    // K: wave stages rows [16w, 16w+16) via 4 async 1KB DMAs
    #pragma unroll
    for (int i = 0; i < 4; i++){
      const int rb = wave * 16 + i * 4;
      gl_lds16(k + bho + (size_t)(kt0 + rb + kl_r) * DH + kl_c, &k_s[rb][0]);
    }
    // V: panel (kt0/64) is 16KB contiguous; wave stages dh [32w, 32w+32)
    const u16* vpan = vtg + ((size_t)bh * 32 + (kt0 >> 6)) * 8192;
    #pragma unroll
    for (int i = 0; i < 4; i++){
      const int rb = wave * 32 + i * 8;
      gl_lds16(vpan + (size_t)(rb + vl_r) * 64 + vl_c, &vt_s[rb][0]);
    }
    __syncthreads();   // compiler drains vmcnt(0) -> DMA complete

    if (kt0 < q0)
      attn_tile<false>(kt0, qbase, wave, row16, quad, qf, k_s, vt_s, p_s, o_acc, l_acc);
    else
      attn_tile<true >(kt0, qbase, wave, row16, quad, qf, k_s, vt_s, p_s, o_acc, l_acc);

    __syncthreads();   // protect restage
  }

  #pragma unroll
  for (int r = 0; r < 4; r++){
    #pragma unroll
    for (int off = 1; off < 16; off <<= 1) l_acc[r] += __shfl_xor(l_acc[r], off, 64);
  }

  const int b = bh >> 4, h = bh & 15;
  #pragma unroll
  for (int nd = 0; nd < 8; nd++){
    #pragma unroll
    for (int r = 0; r < 4; r++){
      const int qr = qbase + quad * 4 + r;
      const size_t off = ((size_t)b * TT + qr) * DM + h * DH + nd * 16 + row16;
      ctx[off] = f2bf(o_acc[nd][r] / l_acc[r]);
    }
  }
}

extern "C" void kernel_launch(void* const* d_in, const int* in_sizes, int n_in,
                              void* d_out, int out_size, void* d_ws, size_t ws_size,
                              hipStream_t stream){
  const float* x  = (const float*)d_in[0];   // fp32 per reference
  const float* wq = (const float*)d_in[1];
  const float* wk = (const float*)d_in[2];
  const float* wv = (const float*)d_in[3];
  const float* wo = (const float*)d_in[4];
  const int* pos  = (const int*)d_in[5];

  char* ws = (char*)d_ws;
  const dim3 tg(64, 64), tb(32, 8);

  if (ws_size >= 92274688ull){
    // fused path: xb 16MB | wt3 25.2MB | qb 16 | kb 16 | vtg 16 = 92.3MB
    u16* xb  = (u16*)ws;                  u16* cb = xb;
    u16* wt3 = (u16*)(ws + 16777216);
    u16* qb  = (u16*)(ws + 41943040);
    u16* kb  = (u16*)(ws + 58720256);
    u16* vtg = (u16*)(ws + 75497472);

    cvt_f32_bf16<<<8192, 256, 0, stream>>>(x, xb, 2097152);
    transpose3<<<dim3(64, 64, 3), tb, 0, stream>>>(wq, wk, wv, wt3);
    gemm_bt3<<<dim3(32, 16, 3), 256, 0, stream>>>(xb, wt3, qb, kb, vtg, 1);
    transpose2048<<<tg, tb, 0, stream>>>(wo, wt3);   // slot0 (wq^T) dead; hoisted
    rope2<<<16384, 256, 0, stream>>>(qb, kb, pos);
    attn_fwd<<<dim3(32, 32), 256, 0, stream>>>(qb, kb, vtg, cb);
    gemm_bt3<<<dim3(32, 16, 1), 256, 0, stream>>>(cb, wt3, d_out, 0, 0, 0);
  } else {
    // fallback (75.5MB): xb/cb 16 | wt 8 | qb 16 | kb 16 | vtg 16
    u16* xb  = (u16*)ws;                  u16* cb = xb;
    u16* wt  = (u16*)(ws + 16777216);
    u16* qb  = (u16*)(ws + 25165824);
    u16* kb  = (u16*)(ws + 41943040);
    u16* vtg = (u16*)(ws + 58720256);

    cvt_f32_bf16<<<8192, 256, 0, stream>>>(x, xb, 2097152);
    transpose2048<<<tg, tb, 0, stream>>>(wq, wt);
    gemm_bt3<<<dim3(32, 16, 1), 256, 0, stream>>>(xb, wt, qb, 0, 0, 1);
    transpose2048<<<tg, tb, 0, stream>>>(wk, wt);
    gemm_bt3<<<dim3(32, 16, 1), 256, 0, stream>>>(xb, wt, kb, 0, 0, 3);
    transpose2048<<<tg, tb, 0, stream>>>(wv, wt);
    gemm_bt3<<<dim3(32, 16, 1), 256, 0, stream>>>(xb, wt, vtg, 0, 0, 2);
    rope2<<<16384, 256, 0, stream>>>(qb, kb, pos);
    attn_fwd<<<dim3(32, 32), 256, 0, stream>>>(qb, kb, vtg, cb);
    transpose2048<<<tg, tb, 0, stream>>>(wo, wt);
    gemm_bt3<<<dim3(32, 16, 1), 256, 0, stream>>>(cb, wt, d_out, 0, 0, 0);
  }
}

// Round 5
// 458.764 us; speedup vs baseline: 1.0517x; 1.0517x over previous
//
#include <hip/hip_runtime.h>
#include <hip/hip_bf16.h>
#include <math.h>

#define NH 16
#define DH 128
#define DM 2048
#define BB 2
#define TT 2048

typedef unsigned short u16;
typedef __attribute__((ext_vector_type(8))) __bf16 bf16x8;
typedef __attribute__((ext_vector_type(8))) u16 u16x8;
typedef __attribute__((ext_vector_type(4))) u16 u16x4;
typedef __attribute__((ext_vector_type(4))) float f32x4;

__device__ __forceinline__ float bf2f(u16 a){
  union { unsigned u; float f; } v; v.u = ((unsigned)a) << 16; return v.f;
}
__device__ __forceinline__ u16 f2bf(float f){
  union { float f; unsigned u; } v; v.f = f;
  unsigned r = v.u + 0x7fffu + ((v.u >> 16) & 1u);  // RNE
  return (u16)(r >> 16);
}

// async global->LDS, 16B per lane. LDS dest = wave-uniform base + lane*16.
typedef const __attribute__((address_space(1))) unsigned int* gas_p;
typedef __attribute__((address_space(3))) unsigned int* las_p;
__device__ __forceinline__ void gl_lds16(const u16* g, u16* lds_uniform_base){
  __builtin_amdgcn_global_load_lds((gas_p)(const void*)g,
                                   (las_p)(void*)lds_uniform_base, 16, 0, 0);
}

#define SB() do{ asm volatile("" ::: "memory"); \
                 __builtin_amdgcn_s_barrier();  \
                 asm volatile("" ::: "memory"); }while(0)
#define WAITV0 asm volatile("s_waitcnt vmcnt(0)" ::: "memory")

// ---------------- fp32 -> bf16 elementwise, 4/thread ----------------
__global__ __launch_bounds__(256)
void cvt_f32_bf16(const float* __restrict__ src, u16* __restrict__ dst, int n4){
  const int i = blockIdx.x * 256 + threadIdx.x;
  if (i >= n4) return;
  const f32x4 v = *(const f32x4*)(src + (size_t)i * 4);
  u16x4 o;
  #pragma unroll
  for (int j = 0; j < 4; j++) o[j] = f2bf(v[j]);
  *(u16x4*)(dst + (size_t)i * 4) = o;
}

// ---------------- W fp32 [K,N] -> Wt bf16 [N,K] (single) ----------------
__global__ __launch_bounds__(256)
void transpose2048(const float* __restrict__ W, u16* __restrict__ Wt){
  __shared__ u16 tile[32][33];
  const int tx = threadIdx.x, ty = threadIdx.y;
  const int bx = blockIdx.x * 32, by = blockIdx.y * 32;
  #pragma unroll
  for (int i = 0; i < 32; i += 8)
    tile[ty + i][tx] = f2bf(W[(size_t)(by + ty + i) * DM + bx + tx]);
  __syncthreads();
  #pragma unroll
  for (int i = 0; i < 32; i += 8)
    Wt[(size_t)(bx + ty + i) * DM + by + tx] = tile[tx][ty + i];
}

// ---------------- 3 weights fused via z ----------------
__global__ __launch_bounds__(256)
void transpose3(const float* __restrict__ w0, const float* __restrict__ w1,
                const float* __restrict__ w2, u16* __restrict__ dst){
  __shared__ u16 tile[32][33];
  const int z = blockIdx.z;
  const float* W = (z == 0) ? w0 : (z == 1) ? w1 : w2;
  u16* Wt = dst + (size_t)z * DM * DM;
  const int tx = threadIdx.x, ty = threadIdx.y;
  const int bx = blockIdx.x * 32, by = blockIdx.y * 32;
  #pragma unroll
  for (int i = 0; i < 32; i += 8)
    tile[ty + i][tx] = f2bf(W[(size_t)(by + ty + i) * DM + bx + tx]);
  __syncthreads();
  #pragma unroll
  for (int i = 0; i < 32; i += 8)
    Wt[(size_t)(bx + ty + i) * DM + by + tx] = tile[tx][ty + i];
}

// ---------------- legacy 128x128 GEMM (fallback path only) ----------
__global__ __launch_bounds__(256)
void gemm_bt(const u16* __restrict__ A, const u16* __restrict__ Bt_base,
             void* __restrict__ C0, u16* __restrict__ Ck, u16* __restrict__ Cv,
             int mode0){
  __shared__ u16 As[2][128][32];
  __shared__ u16 Bs[2][128][32];
  const int z = blockIdx.z;
  const u16* Bt = Bt_base + (size_t)z * DM * DM;
  void* C = (z == 0) ? C0 : (z == 1) ? (void*)Ck : (void*)Cv;
  const int mode = (z == 0) ? mode0 : (z == 1) ? 3 : 2;

  const int tid = threadIdx.x;
  const int wave = tid >> 6, lane = tid & 63;
  const int wm = wave & 1, wn = wave >> 1;
  const int row16 = lane & 15, quad = lane >> 4;
  const int m0 = blockIdx.x * 128, n0 = blockIdx.y * 128;

  const f32x4 zero = {0.f, 0.f, 0.f, 0.f};
  f32x4 acc[4][4];
  #pragma unroll
  for (int i = 0; i < 4; i++)
    #pragma unroll
    for (int j = 0; j < 4; j++) acc[i][j] = zero;

  const int srow = lane >> 2;           // 0..15 within 16-row chunk
  const int scol = (lane & 3) * 8;      // u16 units, 16B per lane

  for (int k0 = 0; k0 < DM; k0 += 64){
    #pragma unroll
    for (int c = 0; c < 2; c++){
      const int rbase = wave * 32 + c * 16;
      const u16* pa = A  + (size_t)(m0 + rbase + srow) * DM + k0 + scol;
      const u16* pb = Bt + (size_t)(n0 + rbase + srow) * DM + k0 + scol;
      gl_lds16(pa,      &As[0][rbase][0]);
      gl_lds16(pa + 32, &As[1][rbase][0]);
      gl_lds16(pb,      &Bs[0][rbase][0]);
      gl_lds16(pb + 32, &Bs[1][rbase][0]);
    }
    __syncthreads();
    #pragma unroll
    for (int buf = 0; buf < 2; buf++){
      bf16x8 af[4], bfr[4];
      #pragma unroll
      for (int mt = 0; mt < 4; mt++)
        af[mt] = *(const bf16x8*)&As[buf][wm * 64 + mt * 16 + row16][quad * 8];
      #pragma unroll
      for (int nt = 0; nt < 4; nt++)
        bfr[nt] = *(const bf16x8*)&Bs[buf][wn * 64 + nt * 16 + row16][quad * 8];
      #pragma unroll
      for (int mt = 0; mt < 4; mt++)
        #pragma unroll
        for (int nt = 0; nt < 4; nt++)
          acc[mt][nt] = __builtin_amdgcn_mfma_f32_16x16x32_bf16(af[mt], bfr[nt], acc[mt][nt], 0, 0, 0);
    }
    __syncthreads();
  }

  #pragma unroll
  for (int mt = 0; mt < 4; mt++){
    #pragma unroll
    for (int nt = 0; nt < 4; nt++){
      #pragma unroll
      for (int r = 0; r < 4; r++){
        const int m = m0 + wm * 64 + mt * 16 + quad * 4 + r;
        const int n = n0 + wn * 64 + nt * 16 + row16;
        const int b = m >> 11, t = m & (TT - 1);
        const int hh = n >> 7, dh = n & (DH - 1);
        if (mode == 1){
          ((u16*)C)[(((size_t)(b * NH + hh) * TT + t) * DH) + dh] = f2bf(acc[mt][nt][r]);
        } else if (mode == 3){
          const int dhs = dh ^ ((t & 7) << 3);
          ((u16*)C)[(((size_t)(b * NH + hh) * TT + t) * DH) + dhs] = f2bf(acc[mt][nt][r]);
        } else if (mode == 2){
          const int ts = (t & 63) ^ ((dh & 7) << 3);
          ((u16*)C)[(((size_t)(b * NH + hh) * 32 + (t >> 6)) * 8192) + dh * 64 + ts] = f2bf(acc[mt][nt][r]);
        } else {
          ((float*)C)[(size_t)m * DM + n] = acc[mt][nt][r];
        }
      }
    }
  }
}

// ---------------- 128x128 GEMM v4: true dbuf, stage-early, 1 bar/tile ------
// Minimal-2-phase (T3 catalog recipe). vs gemm_bt: compute region UNCHANGED
// (16 ds_read + 32 MFMA, one region, compiler fine-lgkmcnt — the R4 lesson),
// but (1) next tile's 8 DMAs issue at TOP of iter into a true double buffer,
// so the vmcnt(0) drain at iter end has the whole compute region as cover
// (gemm_bt: zero cover); (2) ONE barrier per K=64 tile (32 vs 64/GEMM).
// Buffer safety: stage into buf[(t+1)&1] overwrites data last read in iter
// t-1, whose reads precede iter t-1's end barrier. Cost: 64KB LDS -> 2
// blocks/CU; QKV grid 1536 = 3 exact rounds, proj 512 = 1 exact round.
// Bank swizzle for 128B rows (m201 16-way pathology): physical 16B chunk
// c' = c ^ (row&7) via pre-swizzled per-lane GLOBAL source (LDS dest linear);
// fragment reads XOR the same term -> each 8-lane group covers all 32 banks.
__global__ __launch_bounds__(256)
void gemm_bt4(const u16* __restrict__ A, const u16* __restrict__ Bt_base,
              void* __restrict__ C0, u16* __restrict__ Ck, u16* __restrict__ Cv,
              int mode0){
  __shared__ u16 As[2][128][64];   // 2 x 16KB
  __shared__ u16 Bs[2][128][64];   // 2 x 16KB
  const int z = blockIdx.z;
  const u16* Bt = Bt_base + (size_t)z * DM * DM;
  void* C = (z == 0) ? C0 : (z == 1) ? (void*)Ck : (void*)Cv;
  const int mode = (z == 0) ? mode0 : (z == 1) ? 3 : 2;

  const int tid = threadIdx.x;
  const int wave = tid >> 6, lane = tid & 63;
  const int wm = wave & 1, wn = wave >> 1;
  const int row16 = lane & 15, quad = lane >> 4;
  const int m0 = blockIdx.x * 128, n0 = blockIdx.y * 128;

  const f32x4 zero = {0.f, 0.f, 0.f, 0.f};
  f32x4 acc[4][4];
  #pragma unroll
  for (int i = 0; i < 4; i++)
    #pragma unroll
    for (int j = 0; j < 4; j++) acc[i][j] = zero;

  // staging: DMA unit = 8 rows x 128B; lane -> (row lane>>3, chunk lane&7).
  // source k pre-swizzled: physical chunk p holds logical chunk p ^ (row&7).
  const int sr = lane >> 3;                       // row within 8-row unit
  const int sc = ((lane & 7) ^ sr) * 8;           // u16 units (swizzled)
  const u16* aBase = A  + (size_t)(m0 + wave * 32 + sr) * DM + sc;
  const u16* bBase = Bt + (size_t)(n0 + wave * 32 + sr) * DM + sc;

  // wave stages rows [wave*32, wave*32+32): 4 DMAs A + 4 DMAs B
  #define STG4(bf, k0) do{ \
    _Pragma("unroll") \
    for (int j = 0; j < 4; j++){ \
      gl_lds16(aBase + (size_t)(j * 8) * DM + (k0), &As[bf][wave * 32 + j * 8][0]); \
      gl_lds16(bBase + (size_t)(j * 8) * DM + (k0), &Bs[bf][wave * 32 + j * 8][0]); \
    } \
  }while(0)

  // fragment read: logical chunk kk*4+quad at physical (kk*4+quad)^(row&7)
  #define CMP4(bf) do{ \
    bf16x8 af[2][4], bk[2][4]; \
    _Pragma("unroll") \
    for (int kk = 0; kk < 2; kk++){ \
      const int pc = ((kk * 4 + quad) ^ (row16 & 7)) * 8; \
      _Pragma("unroll") \
      for (int mt = 0; mt < 4; mt++) \
        af[kk][mt] = *(const bf16x8*)&As[bf][wm * 64 + mt * 16 + row16][pc]; \
      _Pragma("unroll") \
      for (int nt = 0; nt < 4; nt++) \
        bk[kk][nt] = *(const bf16x8*)&Bs[bf][wn * 64 + nt * 16 + row16][pc]; \
    } \
    __builtin_amdgcn_s_setprio(1); \
    _Pragma("unroll") \
    for (int kk = 0; kk < 2; kk++) \
      _Pragma("unroll") \
      for (int mt = 0; mt < 4; mt++) \
        _Pragma("unroll") \
        for (int nt = 0; nt < 4; nt++) \
          acc[mt][nt] = __builtin_amdgcn_mfma_f32_16x16x32_bf16(af[kk][mt], bk[kk][nt], acc[mt][nt], 0, 0, 0); \
    __builtin_amdgcn_s_setprio(0); \
  }while(0)

  // prologue: tile 0 -> buf 0
  STG4(0, 0);
  WAITV0; SB();

  for (int t = 0; t < 31; ++t){
    STG4((t + 1) & 1, (t + 1) * 64);  // issue-early: covered by compute below
    CMP4(t & 1);
    WAITV0;                            // only tile t+1's 8 loads outstanding
    SB();
  }
  CMP4(1);                             // tile 31 (31&1 == 1), no prefetch

  #undef STG4
  #undef CMP4

  // epilogue: C/D layout row = quad*4+reg, col = lane&15
  #pragma unroll
  for (int mt = 0; mt < 4; mt++){
    #pragma unroll
    for (int nt = 0; nt < 4; nt++){
      #pragma unroll
      for (int r = 0; r < 4; r++){
        const int m = m0 + wm * 64 + mt * 16 + quad * 4 + r;
        const int n = n0 + wn * 64 + nt * 16 + row16;
        const int b = m >> 11, t = m & (TT - 1);
        const int hh = n >> 7, dh = n & (DH - 1);
        if (mode == 1){
          ((u16*)C)[(((size_t)(b * NH + hh) * TT + t) * DH) + dh] = f2bf(acc[mt][nt][r]);
        } else if (mode == 3){
          const int dhs = dh ^ ((t & 7) << 3);
          ((u16*)C)[(((size_t)(b * NH + hh) * TT + t) * DH) + dhs] = f2bf(acc[mt][nt][r]);
        } else if (mode == 2){
          const int ts = (t & 63) ^ ((dh & 7) << 3);
          ((u16*)C)[(((size_t)(b * NH + hh) * 32 + (t >> 6)) * 8192) + dh * 64 + ts] = f2bf(acc[mt][nt][r]);
        } else {
          ((float*)C)[(size_t)m * DM + n] = acc[mt][nt][r];
        }
      }
    }
  }
}

// ---------------- fused RoPE on q (normal) AND k (swizzled storage) --------
__global__ __launch_bounds__(256)
void rope2(u16* __restrict__ qb, u16* __restrict__ kb, const int* __restrict__ posp){
  const int idx = blockIdx.x * 256 + threadIdx.x;   // one per (row, pair-slot)
  const int pair = idx & 63;
  const int row = idx >> 6;                          // b*H*T + h*T + t
  const int t = row & (TT - 1);
  int p0 = *posp; if (p0 < 0) p0 = 0;
  const float tf = (float)(p0 + t);
  const size_t base = (size_t)row * DH;
  // q: storage pair == logical pair
  {
    const float inv = expf(-(float)pair * (9.2103403719761836f / 64.f));
    float sn, cs; sincosf(tf * inv, &sn, &cs);
    const float q1 = bf2f(qb[base + pair]);
    const float q2 = bf2f(qb[base + 64 + pair]);
    qb[base + pair]      = f2bf(q1 * cs - q2 * sn);
    qb[base + 64 + pair] = f2bf(q1 * sn + q2 * cs);
  }
  // k: storage slot `pair` holds logical dh = pair ^ ((t&7)<<3)
  {
    const int pl = pair ^ ((t & 7) << 3);
    const float inv = expf(-(float)pl * (9.2103403719761836f / 64.f));
    float sn, cs; sincosf(tf * inv, &sn, &cs);
    const float k1 = bf2f(kb[base + pair]);
    const float k2 = bf2f(kb[base + 64 + pair]);
    kb[base + pair]      = f2bf(k1 * cs - k2 * sn);
    kb[base + 64 + pair] = f2bf(k1 * sn + k2 * cs);
  }
}

// ---------------- causal flash attention v6 + T5 setprio -------------------
template<bool MASK>
__device__ __forceinline__ void attn_tile(
    int kt0, int qbase, int wave, int row16, int quad,
    const bf16x8 (&qf)[4],
    u16 (&k_s)[64][128], u16 (&vt_s)[128][64], u16 (&p_s)[4][16][72],
    f32x4 (&o_acc)[8], float (&l_acc)[4])
{
  const float scale = 0.08838834764831845f;  // 1/sqrt(128)
  const f32x4 zero = {0.f, 0.f, 0.f, 0.f};
  const int fx = (row16 & 7) << 3;           // XOR de-swizzle
  f32x4 s_acc[4];
  #pragma unroll
  for (int nt = 0; nt < 4; nt++) s_acc[nt] = zero;
  __builtin_amdgcn_s_setprio(1);
  #pragma unroll
  for (int st = 0; st < 4; st++)
    #pragma unroll
    for (int nt = 0; nt < 4; nt++){
      const bf16x8 kf = *(const bf16x8*)&k_s[nt * 16 + row16][(st * 32 + quad * 8) ^ fx];
      s_acc[nt] = __builtin_amdgcn_mfma_f32_16x16x32_bf16(qf[st], kf, s_acc[nt], 0, 0, 0);
    }
  __builtin_amdgcn_s_setprio(0);
  #pragma unroll
  for (int r = 0; r < 4; r++){
    float ps = 0.f;
    #pragma unroll
    for (int nt = 0; nt < 4; nt++){
      float p = __expf(s_acc[nt][r] * scale);
      if (MASK){
        const int qr = qbase + quad * 4 + r;
        if (kt0 + nt * 16 + row16 > qr) p = 0.f;
      }
      ps += p;
      p_s[wave][quad * 4 + r][nt * 16 + row16] = f2bf(p);
    }
    l_acc[r] += ps;
  }
  asm volatile("" ::: "memory");  // p_s wave-private; DS in-order per wave

  __builtin_amdgcn_s_setprio(1);
  #pragma unroll
  for (int kk = 0; kk < 2; kk++){
    const bf16x8 pf = *(const bf16x8*)&p_s[wave][row16][kk * 32 + quad * 8];
    #pragma unroll
    for (int nd = 0; nd < 8; nd++){
      const bf16x8 vb = *(const bf16x8*)&vt_s[nd * 16 + row16][(kk * 32 + quad * 8) ^ fx];
      o_acc[nd] = __builtin_amdgcn_mfma_f32_16x16x32_bf16(pf, vb, o_acc[nd], 0, 0, 0);
    }
  }
  __builtin_amdgcn_s_setprio(0);
}

__global__ __launch_bounds__(256)
void attn_fwd(const u16* __restrict__ q, const u16* __restrict__ k,
              const u16* __restrict__ vtg, u16* __restrict__ ctx){
  __shared__ u16 k_s[64][128];     // dense [key][dh'], DMA-staged
  __shared__ u16 vt_s[128][64];    // dense [dh][t'], DMA-staged
  __shared__ u16 p_s[4][16][72];   // per-wave P [q][key]
  const int tid = threadIdx.x;
  const int wave = tid >> 6, lane = tid & 63;
  const int row16 = lane & 15, quad = lane >> 4;
  const int bh = blockIdx.y;
  const int q0 = (31 - blockIdx.x) * 64;   // heavy blocks dispatch first
  const int qbase = q0 + wave * 16;
  const size_t bho = (size_t)bh * TT * DH;

  bf16x8 qf[4];
  {
    const u16* qp = q + bho + (size_t)(qbase + row16) * DH + quad * 8;
    #pragma unroll
    for (int st = 0; st < 4; st++) qf[st] = *(const bf16x8*)(qp + st * 32);
  }

  float l_acc[4] = {0.f, 0.f, 0.f, 0.f};
  const f32x4 zero = {0.f, 0.f, 0.f, 0.f};
  f32x4 o_acc[8];
  #pragma unroll
  for (int i = 0; i < 8; i++) o_acc[i] = zero;

  // DMA lane maps: K 1KB = 4 rows x 256B; V 1KB = 8 rows x 128B
  const int kl_r = lane >> 4, kl_c = (lane & 15) * 8;
  const int vl_r = lane >> 3, vl_c = (lane & 7) * 8;

  for (int kt0 = 0; kt0 < q0 + 64; kt0 += 64){
    // K: wave stages rows [16w, 16w+16) via 4 async 1KB DMAs
    #pragma unroll
    for (int i = 0; i < 4; i++){
      const int rb = wave * 16 + i * 4;
      gl_lds16(k + bho + (size_t)(kt0 + rb + kl_r) * DH + kl_c, &k_s[rb][0]);
    }
    // V: panel (kt0/64) is 16KB contiguous; wave stages dh [32w, 32w+32)
    const u16* vpan = vtg + ((size_t)bh * 32 + (kt0 >> 6)) * 8192;
    #pragma unroll
    for (int i = 0; i < 4; i++){
      const int rb = wave * 32 + i * 8;
      gl_lds16(vpan + (size_t)(rb + vl_r) * 64 + vl_c, &vt_s[rb][0]);
    }
    __syncthreads();   // compiler drains vmcnt(0) -> DMA complete

    if (kt0 < q0)
      attn_tile<false>(kt0, qbase, wave, row16, quad, qf, k_s, vt_s, p_s, o_acc, l_acc);
    else
      attn_tile<true >(kt0, qbase, wave, row16, quad, qf, k_s, vt_s, p_s, o_acc, l_acc);

    __syncthreads();   // protect restage
  }

  #pragma unroll
  for (int r = 0; r < 4; r++){
    #pragma unroll
    for (int off = 1; off < 16; off <<= 1) l_acc[r] += __shfl_xor(l_acc[r], off, 64);
  }

  const int b = bh >> 4, h = bh & 15;
  #pragma unroll
  for (int nd = 0; nd < 8; nd++){
    #pragma unroll
    for (int r = 0; r < 4; r++){
      const int qr = qbase + quad * 4 + r;
      const size_t off = ((size_t)b * TT + qr) * DM + h * DH + nd * 16 + row16;
      ctx[off] = f2bf(o_acc[nd][r] / l_acc[r]);
    }
  }
}

extern "C" void kernel_launch(void* const* d_in, const int* in_sizes, int n_in,
                              void* d_out, int out_size, void* d_ws, size_t ws_size,
                              hipStream_t stream){
  const float* x  = (const float*)d_in[0];   // fp32 per reference
  const float* wq = (const float*)d_in[1];
  const float* wk = (const float*)d_in[2];
  const float* wv = (const float*)d_in[3];
  const float* wo = (const float*)d_in[4];
  const int* pos  = (const int*)d_in[5];

  char* ws = (char*)d_ws;
  const dim3 tg(64, 64), tb(32, 8);

  if (ws_size >= 92274688ull){
    // fused path: xb 16MB | wt3 25.2MB | qb 16 | kb 16 | vtg 16 = 92.3MB
    u16* xb  = (u16*)ws;                  u16* cb = xb;
    u16* wt3 = (u16*)(ws + 16777216);
    u16* qb  = (u16*)(ws + 41943040);
    u16* kb  = (u16*)(ws + 58720256);
    u16* vtg = (u16*)(ws + 75497472);

    cvt_f32_bf16<<<8192, 256, 0, stream>>>(x, xb, 2097152);
    transpose3<<<dim3(64, 64, 3), tb, 0, stream>>>(wq, wk, wv, wt3);
    gemm_bt4<<<dim3(32, 16, 3), 256, 0, stream>>>(xb, wt3, qb, kb, vtg, 1);
    transpose2048<<<tg, tb, 0, stream>>>(wo, wt3);   // slot0 (wq^T) dead; hoisted
    rope2<<<16384, 256, 0, stream>>>(qb, kb, pos);
    attn_fwd<<<dim3(32, 32), 256, 0, stream>>>(qb, kb, vtg, cb);
    gemm_bt4<<<dim3(32, 16, 1), 256, 0, stream>>>(cb, wt3, d_out, 0, 0, 0);
  } else {
    // fallback (75.5MB): xb/cb 16 | wt 8 | qb 16 | kb 16 | vtg 16
    u16* xb  = (u16*)ws;                  u16* cb = xb;
    u16* wt  = (u16*)(ws + 16777216);
    u16* qb  = (u16*)(ws + 25165824);
    u16* kb  = (u16*)(ws + 41943040);
    u16* vtg = (u16*)(ws + 58720256);

    cvt_f32_bf16<<<8192, 256, 0, stream>>>(x, xb, 2097152);
    transpose2048<<<tg, tb, 0, stream>>>(wq, wt);
    gemm_bt<<<dim3(32, 16, 1), 256, 0, stream>>>(xb, wt, qb, 0, 0, 1);
    transpose2048<<<tg, tb, 0, stream>>>(wk, wt);
    gemm_bt<<<dim3(32, 16, 1), 256, 0, stream>>>(xb, wt, kb, 0, 0, 3);
    transpose2048<<<tg, tb, 0, stream>>>(wv, wt);
    gemm_bt<<<dim3(32, 16, 1), 256, 0, stream>>>(xb, wt, vtg, 0, 0, 2);
    rope2<<<16384, 256, 0, stream>>>(qb, kb, pos);
    attn_fwd<<<dim3(32, 32), 256, 0, stream>>>(qb, kb, vtg, cb);
    transpose2048<<<tg, tb, 0, stream>>>(wo, wt);
    gemm_bt<<<dim3(32, 16, 1), 256, 0, stream>>>(cb, wt, d_out, 0, 0, 0);
  }
}